// Round 18
// baseline (3640.018 us; speedup 1.0000x reference)
//
#include <hip/hip_runtime.h>

// Problem sizes (fixed by the reference)
constexpr int B = 128, S = 1024, E = 256, H = 512, V = 128;
constexpr int NGROUP = 8, WPG = 15, NWG = 128;  // 8 groups x 16 slots (15 live)
constexpr int GB = B / NGROUP;                  // 16 batch rows per group
constexpr int NT = 512;                         // threads per WG (8 waves)
constexpr int FSTRIDE = 16;                     // flag slot stride (u32) = 64B line
constexpr unsigned LDS_BYTES = 32768;           // AH 16KB + AL 16KB

using short8 = __attribute__((ext_vector_type(8))) short;   // 8 bf16 = 4 VGPRs
using f32x4  = __attribute__((ext_vector_type(4))) float;   // MFMA acc
using u16    = unsigned short;

#define MFMA_B16(a, b, c) __builtin_amdgcn_mfma_f32_16x16x32_bf16((a), (b), (c), 0, 0, 0)

// ---- bf16 helpers ------------------------------------------------------------
// truncation split (activations: v = hi + lo, ~2^-16 rel error)
__device__ __forceinline__ unsigned pk(float a, float b) {
  return (__builtin_bit_cast(unsigned, b) & 0xFFFF0000u) |
         (__builtin_bit_cast(unsigned, a) >> 16);
}
__device__ __forceinline__ float hif(float a) {
  return __builtin_bit_cast(float, __builtin_bit_cast(unsigned, a) & 0xFFFF0000u);
}
// round-to-nearest-even bf16 (weights, single plane, 2^-9 rel error)
__device__ __forceinline__ unsigned rne(float a) {
  unsigned u = __builtin_bit_cast(unsigned, a);
  return (u + 0x7FFFu + ((u >> 16) & 1u)) >> 16;
}
__device__ __forceinline__ unsigned pkr(float a, float b) {
  return (rne(b) << 16) | rne(a);
}
__device__ __forceinline__ void cvt16(const float4& v0, const float4& v1,
                                      const float4& v2, const float4& v3,
                                      uint4& h0, uint4& h1, uint4& l0, uint4& l1) {
  h0 = make_uint4(pk(v0.x, v0.y), pk(v0.z, v0.w), pk(v1.x, v1.y), pk(v1.z, v1.w));
  h1 = make_uint4(pk(v2.x, v2.y), pk(v2.z, v2.w), pk(v3.x, v3.y), pk(v3.z, v3.w));
  l0 = make_uint4(pk(v0.x - hif(v0.x), v0.y - hif(v0.y)),
                  pk(v0.z - hif(v0.z), v0.w - hif(v0.w)),
                  pk(v1.x - hif(v1.x), v1.y - hif(v1.y)),
                  pk(v1.z - hif(v1.z), v1.w - hif(v1.w)));
  l1 = make_uint4(pk(v2.x - hif(v2.x), v2.y - hif(v2.y)),
                  pk(v2.z - hif(v2.z), v2.w - hif(v2.w)),
                  pk(v3.x - hif(v3.x), v3.y - hif(v3.y)),
                  pk(v3.z - hif(v3.z), v3.w - hif(v3.w)));
}

// fast tanh via hardware exp (round-8/12 proven: same absmax as tanhf)
__device__ __forceinline__ float ftanh(float x) {
  float e = __expf(2.0f * x);
  return 1.0f - 2.0f * __builtin_amdgcn_rcpf(e + 1.0f);
}

// ---- system-scope (cross-XCD, fence-free) memory helpers --------------------
__device__ __forceinline__ void stg_sys_f32(float* p, float v) {
  asm volatile("global_store_dword %0, %1, off sc0 sc1" :: "v"(p), "v"(v) : "memory");
}
__device__ __forceinline__ void stg_sys_u32(unsigned* p, unsigned v) {
  asm volatile("global_store_dword %0, %1, off sc0 sc1" :: "v"(p), "v"(v) : "memory");
}
__device__ __forceinline__ void stg_sys_u16(u16* p, unsigned v) {
  asm volatile("global_store_short %0, %1, off sc0 sc1" :: "v"(p), "v"(v) : "memory");
}

// Group barrier (r17-proven): cacheline-spread flag slots (64B apart), no RMW,
// no cache-maintenance fences. vmcnt(0) drains own sc stores; tid0 publishes;
// wave0 lanes poll with s_sleep backoff. Cap -> fail-visible.
__device__ __forceinline__ void gbar(unsigned* slots, int r, unsigned target, int tid) {
  asm volatile("s_waitcnt vmcnt(0)" ::: "memory");
  __syncthreads();
  if (tid < 64) {
    if (tid == 0)
      asm volatile("global_store_dword %0, %1, off sc0 sc1"
                   :: "v"(slots + r * FSTRIDE), "v"(target) : "memory");
    int cap = 0;
    for (;;) {
      unsigned v = target;
      if (tid < WPG)
        asm volatile("global_load_dword %0, %1, off sc0 sc1\n\ts_waitcnt vmcnt(0)"
                     : "=v"(v) : "v"(slots + tid * FSTRIDE) : "memory");
      if (__all((int)(v >= target))) break;
      __builtin_amdgcn_s_sleep(1);
      if (++cap > (1 << 22)) break;  // fail-visible instead of hanging
    }
  }
  __syncthreads();
}

// ---- W fragment -> registers (SINGLE bf16 plane, RNE): lane holds
// W[col0+(lane&15)][ks*32 + (lane>>4)*8 .. +8] as one short8 per ks. ----------
template <int KK>
__device__ __forceinline__ void loadWfrag(const float* W, int col0, int lane,
                                          short8* wh) {
  const int lc = col0 + (lane & 15);
  const int q = lane >> 4;
#pragma unroll
  for (int ks = 0; ks < KK / 32; ++ks) {
    const float* src = W + (size_t)lc * KK + ks * 32 + q * 8;
    float4 a = *(const float4*)src;
    float4 b = *(const float4*)(src + 4);
    uint4 h = make_uint4(pkr(a.x, a.y), pkr(a.z, a.w), pkr(b.x, b.y), pkr(b.z, b.w));
    wh[ks] = __builtin_bit_cast(short8, h);
  }
}

// ---- A staging: bf16 hi/lo state planes ([16][512] u16) -> LDS --------------
// 512 threads x 2 chunks x 16B per plane = 16KB per plane.
__device__ __forceinline__ void compute_offs(int tid, int* off, int* lof) {
#pragma unroll
  for (int it = 0; it < 2; ++it) {
    int s = tid + it * NT, rr = s >> 6, ks = s & 63;   // 64 x 16B chunks per row
    off[it] = rr * 1024 + ks * 16;
    lof[it] = off[it] ^ ((rr & 7) << 4);
  }
}
__device__ __forceinline__ void stage4(int tid, const u16* Ph, const u16* Pl,
                                       char* AH, char* AL) {
  int off[2], lof[2];
  compute_offs(tid, off, lof);
  const char* gh = (const char*)Ph;
  const char* gl = (const char*)Pl;
  float4 o0, o1, o2, o3;
  asm volatile(
      "global_load_dwordx4 %0, %4, off sc0 sc1\n\t"
      "global_load_dwordx4 %1, %5, off sc0 sc1\n\t"
      "global_load_dwordx4 %2, %6, off sc0 sc1\n\t"
      "global_load_dwordx4 %3, %7, off sc0 sc1\n\t"
      "s_waitcnt vmcnt(0)"
      : "=&v"(o0), "=&v"(o1), "=&v"(o2), "=&v"(o3)
      : "v"(gh + off[0]), "v"(gh + off[1]), "v"(gl + off[0]), "v"(gl + off[1])
      : "memory");
  *(float4*)(AH + lof[0]) = o0; *(float4*)(AH + lof[1]) = o1;
  *(float4*)(AL + lof[0]) = o2; *(float4*)(AL + lof[1]) = o3;
}
__device__ __forceinline__ void stage8i(int tid, const u16* Ph, const u16* Pl,
                                        char* AH, char* AL,
                                        const float* q0, const float* q1,
                                        const float* q2, const float* q3,
                                        float& i0, float& i1, float& i2, float& i3) {
  int off[2], lof[2];
  compute_offs(tid, off, lof);
  const char* gh = (const char*)Ph;
  const char* gl = (const char*)Pl;
  float4 o0, o1, o2, o3;
  asm volatile(
      "global_load_dword %4, %12, off sc0 sc1\n\t"
      "global_load_dword %5, %13, off sc0 sc1\n\t"
      "global_load_dword %6, %14, off sc0 sc1\n\t"
      "global_load_dword %7, %15, off sc0 sc1\n\t"
      "global_load_dwordx4 %0, %8, off sc0 sc1\n\t"
      "global_load_dwordx4 %1, %9, off sc0 sc1\n\t"
      "global_load_dwordx4 %2, %10, off sc0 sc1\n\t"
      "global_load_dwordx4 %3, %11, off sc0 sc1\n\t"
      "s_waitcnt vmcnt(0)"
      : "=&v"(o0), "=&v"(o1), "=&v"(o2), "=&v"(o3),
        "=&v"(i0), "=&v"(i1), "=&v"(i2), "=&v"(i3)
      : "v"(gh + off[0]), "v"(gh + off[1]), "v"(gl + off[0]), "v"(gl + off[1]),
        "v"(q0), "v"(q1), "v"(q2), "v"(q3)
      : "memory");
  *(float4*)(AH + lof[0]) = o0; *(float4*)(AH + lof[1]) = o1;
  *(float4*)(AL + lof[0]) = o2; *(float4*)(AL + lof[1]) = o3;
}

// ---- bf16x2 MFMA loop: acts hi/lo from LDS, single-plane W from registers ---
// (hi+lo)*w = hi*w + lo*w accumulated into ONE acc.
template <int KK>
__device__ __forceinline__ f32x4 mm_frag_reg(const char* AH, const char* AL,
                                             const short8* wh, int lane) {
  constexpr int ROWB = KK * 2;
  const int rr = lane & 15;
  const int kq = (lane >> 4) * 16;
  const int swa = (rr & 7) << 4;
  f32x4 a0 = {0.f, 0.f, 0.f, 0.f};
#pragma unroll
  for (int ks = 0; ks < KK / 32; ++ks) {
    int ka = rr * ROWB + ks * 64 + kq;
    short8 ah = *(const short8*)(AH + (ka ^ swa));
    short8 al = *(const short8*)(AL + (ka ^ swa));
    a0 = MFMA_B16(ah, wh[ks], a0);
    a0 = MFMA_B16(al, wh[ks], a0);
  }
  return a0;
}

// ---- per-role phase loops (each WG owns 128 cols = 8 waves x 16) ------------
// role h (h0: dt=1, h1: dt=3): h[t] = tanh(im[t] + h[t-1] @ W^T)
__device__ __forceinline__ void run_h(
    int tid, int lane, int w, unsigned* slots, int r, int dt,
    u16* hh, u16* hl, const float* imb, float* hn2base,
    const float* Wsrc, int tn, char* AH, char* AL) {
  short8 wh[16];
  loadWfrag<512>(Wsrc, tn * 128 + w * 16, lane, wh);
  gbar(slots, r, 1, tid);
  const int lc15 = lane & 15, r0 = (lane >> 4) * 4;
  const int gcol = tn * 128 + w * 16 + lc15;
  for (int p = 0; p <= S + 3; ++p) {
    int t = p - dt;
    if (t >= 0 && t < S) {
      const u16* Ph = hh + ((t - 1) & 1) * 8192;
      const u16* Pl = hl + ((t - 1) & 1) * 8192;
      const float* iq = imb + (t & 1) * 8192 + (size_t)r0 * H + gcol;
      float i0, i1, i2, i3;
      stage8i(tid, Ph, Pl, AH, AL, iq, iq + H, iq + 2 * H, iq + 3 * H, i0, i1, i2, i3);
      __syncthreads();
      f32x4 s = mm_frag_reg<512>(AH, AL, wh, lane);
      u16* Dh = hh + (t & 1) * 8192;
      u16* Dl = hl + (t & 1) * 8192;
      float iv[4] = {i0, i1, i2, i3};
      bool last = (t == S - 1);
#pragma unroll
      for (int j = 0; j < 4; ++j) {
        float v = ftanh(s[j] + iv[j]);
        unsigned ub = __builtin_bit_cast(unsigned, v);
        float lov = v - __builtin_bit_cast(float, ub & 0xFFFF0000u);
        stg_sys_u16(Dh + (size_t)(r0 + j) * H + gcol, ub >> 16);
        stg_sys_u16(Dl + (size_t)(r0 + j) * H + gcol,
                    __builtin_bit_cast(unsigned, lov) >> 16);
        if (last) hn2base[(size_t)(r0 + j) * H + gcol] = v;
      }
    }
    gbar(slots, r, 2 + p, tid);
  }
}

// role G: G[t] = b_ih1 + b_hh1 + h0[t] @ W_ih1^T  (fp32 out)
__device__ __forceinline__ void run_g(
    int tid, int lane, int w, unsigned* slots, int r,
    const u16* h0h, const u16* h0l, float* Gg,
    const float* b1, const float* b2,
    const float* Wsrc, int tn, char* AH, char* AL) {
  short8 wh[16];
  loadWfrag<512>(Wsrc, tn * 128 + w * 16, lane, wh);
  gbar(slots, r, 1, tid);
  const int lc15 = lane & 15, r0 = (lane >> 4) * 4;
  const int gcol = tn * 128 + w * 16 + lc15;
  const float bsum = b1[gcol] + b2[gcol];
  for (int p = 0; p <= S + 3; ++p) {
    int t = p - 2;
    if (t >= 0 && t < S) {
      stage4(tid, h0h + (t & 1) * 8192, h0l + (t & 1) * 8192, AH, AL);
      __syncthreads();
      f32x4 s = mm_frag_reg<512>(AH, AL, wh, lane);
      float* D = Gg + (t & 1) * 8192;
#pragma unroll
      for (int j = 0; j < 4; ++j)
        stg_sys_f32(D + (size_t)(r0 + j) * H + gcol, s[j] + bsum);
    }
    gbar(slots, r, 2 + p, tid);
  }
}

// role Ain: Ain[t] = b_ih0 + b_hh0 + emb[x[:,t]] @ W_ih0^T  (256 cols per WG)
__device__ __forceinline__ void run_ain(
    int tid, int lane, int w, unsigned* slots, int r,
    const int* x, const float* emb, float* Ain,
    const float* b1, const float* b2,
    const float* Wsrc, int a, int gb0, char* AH, char* AL) {
  short8 whA[8], whB[8];
  const int col0 = a * 256 + w * 32;
  loadWfrag<256>(Wsrc, col0, lane, whA);
  loadWfrag<256>(Wsrc, col0 + 16, lane, whB);
  gbar(slots, r, 1, tid);
  const int lc15 = lane & 15, r0 = (lane >> 4) * 4;
  const int gcolA = col0 + lc15, gcolB = gcolA + 16;
  const float bsA = b1[gcolA] + b2[gcolA], bsB = b1[gcolB] + b2[gcolB];
  const int rr = tid >> 4, q = tid & 15;   // first 256 threads stage
  for (int p = 0; p <= S + 3; ++p) {
    int t = p;
    if (t < S) {
      if (tid < 256) {
        int idx = x[(size_t)(gb0 + rr) * S + t];
        const float4* src = (const float4*)(emb + (size_t)idx * E + q * 16);
        float4 v0 = src[0], v1 = src[1], v2 = src[2], v3 = src[3];
        uint4 h0v, h1v, l0v, l1v;
        cvt16(v0, v1, v2, v3, h0v, h1v, l0v, l1v);
        int bb = rr * 512 + q * 32, sw = (rr & 7) << 4;
        *(uint4*)(AH + ((bb) ^ sw)) = h0v;
        *(uint4*)(AH + ((bb + 16) ^ sw)) = h1v;
        *(uint4*)(AL + ((bb) ^ sw)) = l0v;
        *(uint4*)(AL + ((bb + 16) ^ sw)) = l1v;
      }
      __syncthreads();
      f32x4 sA = mm_frag_reg<256>(AH, AL, whA, lane);
      f32x4 sB = mm_frag_reg<256>(AH, AL, whB, lane);
      float* D = Ain + (t & 1) * 8192;
#pragma unroll
      for (int j = 0; j < 4; ++j) {
        stg_sys_f32(D + (size_t)(r0 + j) * H + gcolA, sA[j] + bsA);
        stg_sys_f32(D + (size_t)(r0 + j) * H + gcolB, sB[j] + bsB);
      }
    }
    gbar(slots, r, 2 + p, tid);
  }
}

// role logits: out[t] = b_out + h1[t] @ W_out^T (one WG, 8 waves x 16 = 128 V)
__device__ __forceinline__ void run_out(
    int tid, int lane, int w, unsigned* slots, int r,
    const u16* h1h, const u16* h1l, float* out, const float* b_out,
    const float* Wsrc, int gb0, char* AH, char* AL) {
  short8 wh[16];
  loadWfrag<512>(Wsrc, w * 16, lane, wh);
  gbar(slots, r, 1, tid);
  const int lc15 = lane & 15, r0 = (lane >> 4) * 4;
  const int gcol = w * 16 + lc15;
  const float bv = b_out[gcol];
  for (int p = 0; p <= S + 3; ++p) {
    int t = p - 4;
    if (t >= 0 && t < S) {
      stage4(tid, h1h + (t & 1) * 8192, h1l + (t & 1) * 8192, AH, AL);
      __syncthreads();
      f32x4 s = mm_frag_reg<512>(AH, AL, wh, lane);
#pragma unroll
      for (int j = 0; j < 4; ++j)
        out[((size_t)(gb0 + r0 + j) * S + t) * V + gcol] = s[j] + bv;
    }
    gbar(slots, r, 2 + p, tid);
  }
}

// Grouping by blockIdx (placement-independent correctness, G16).
// Roles within a 15-WG group (16 batch rows, 512-thread WGs):
//  r [0,4): h0 t=p-1 | r [4,8): G t=p-2 | r [8,12): h1 t=p-3
//  r [12,14): Ain t=p (256 cols) | r 14: logits t=p-4
__global__ void __launch_bounds__(NT, 1) rnn_pers(
    const int* __restrict__ x, const float* __restrict__ emb,
    const float* __restrict__ W_ih0, const float* __restrict__ b_ih0,
    const float* __restrict__ W_hh0, const float* __restrict__ b_hh0,
    const float* __restrict__ W_ih1, const float* __restrict__ b_ih1,
    const float* __restrict__ W_hh1, const float* __restrict__ b_hh1,
    const float* __restrict__ W_out, const float* __restrict__ b_out,
    float* __restrict__ out, float* __restrict__ ws)
{
  extern __shared__ char lds[];
  char* AH = lds;
  char* AL = lds + 16384;

  const int tid = threadIdx.x;
  const int g = blockIdx.x >> 4;
  const int r = blockIdx.x & 15;
  if (r >= WPG) return;

  unsigned* slots = (unsigned*)ws + (size_t)g * (WPG * FSTRIDE + 16);
  float* base = ws + 2048 + (size_t)g * 65536;
  float* Ain = base;                 // fp32 [2][16][512]
  float* Gg  = base + 16384;         // fp32 [2][16][512]
  u16* h0h = (u16*)(base + 32768);   // bf16-hi/lo [2][16][512] x4 planes
  u16* h0l = h0h + 16384;
  u16* h1h = h0h + 32768;
  u16* h1l = h0h + 49152;
  const int gb0 = g * GB;

  // Zero h-state planes (both slots, 4 planes = 32768 u32), system scope.
  {
    unsigned* zp = (unsigned*)h0h;
    for (int i = r * NT + tid; i < 32768; i += WPG * NT) stg_sys_u32(zp + i, 0u);
  }

  const int lane = tid & 63, w = tid >> 6;
  float* hn = out + (size_t)B * S * V;

  if (r < 4)
    run_h(tid, lane, w, slots, r, 1, h0h, h0l, Ain,
          hn + (size_t)gb0 * H, W_hh0, r, AH, AL);
  else if (r < 8)
    run_g(tid, lane, w, slots, r, h0h, h0l, Gg, b_ih1, b_hh1,
          W_ih1, r - 4, AH, AL);
  else if (r < 12)
    run_h(tid, lane, w, slots, r, 3, h1h, h1l, Gg,
          hn + (size_t)B * H + (size_t)gb0 * H, W_hh1, r - 8, AH, AL);
  else if (r < 14)
    run_ain(tid, lane, w, slots, r, x, emb, Ain, b_ih0, b_hh0,
            W_ih0, r - 12, gb0, AH, AL);
  else
    run_out(tid, lane, w, slots, r, h1h, h1l, out, b_out,
            W_out, gb0, AH, AL);
}

extern "C" void kernel_launch(void* const* d_in, const int* in_sizes, int n_in,
                              void* d_out, int out_size, void* d_ws, size_t ws_size,
                              hipStream_t stream) {
  const int*   x     = (const int*)d_in[0];
  const float* emb   = (const float*)d_in[1];
  const float* W_ih0 = (const float*)d_in[2];
  const float* b_ih0 = (const float*)d_in[3];
  const float* W_hh0 = (const float*)d_in[4];
  const float* b_hh0 = (const float*)d_in[5];
  const float* W_ih1 = (const float*)d_in[6];
  const float* b_ih1 = (const float*)d_in[7];
  const float* W_hh1 = (const float*)d_in[8];
  const float* b_hh1 = (const float*)d_in[9];
  const float* W_out = (const float*)d_in[10];
  const float* b_out = (const float*)d_in[11];
  float* out = (float*)d_out;
  float* ws  = (float*)d_ws;

  hipFuncSetAttribute((const void*)rnn_pers,
                      hipFuncAttributeMaxDynamicSharedMemorySize, (int)LDS_BYTES);
  // Zero the (cacheline-spread) barrier flag region: 8 groups x 256 u32 = 8KB.
  hipMemsetAsync(ws, 0, 8192, stream);

  void* args[] = { &x, &emb, &W_ih0, &b_ih0, &W_hh0, &b_hh0, &W_ih1, &b_ih1,
                   &W_hh1, &b_hh1, &W_out, &b_out, &out, &ws };
  hipLaunchCooperativeKernel((const void*)rnn_pers, dim3(NWG), dim3(NT),
                             args, LDS_BYTES, stream);
}